// Round 7
// baseline (87.324 us; speedup 1.0000x reference)
//
#include <hip/hip_runtime.h>
#include <hip/hip_fp16.h>

#define BB 4
#define NN 2048
#define DD 256
#define TILE_N 32                 // n per block
#define NPW 8                     // n per wave (4 waves * 8 = 32)
#define NT (NN / TILE_N)          // 64 n-tiles
#define MSPLIT 2                  // m-range halves
#define MLEN (NN / MSPLIT)        // 1024 m per block
#define MCH (MLEN / 128)          // 8 chunks of 128 m (2 points/lane)
#define WQ_CAP 96                 // per-wave hit queue (lambda ~5.4)
#define NBLK (BB * BB * NT * MSPLIT)   // 2048 scan blocks

// Kernel 1: pack features into unit-norm fp16 rows.
// One wave per row: f32 norm (butterfly leaves sum in all lanes), scale,
// convert lane's 4 floats -> 4 halves (8 B store). 8 MB read + 4 MB write.
// Rationale (r6 post-mortem): tail streamed ~88 MB of random f32 feature
// rows through L3 (~37 us). Unit-fp16 rows halve bytes AND fit in one
// XCD's 4 MiB L2, and kill all per-hit norm work.
__global__ __launch_bounds__(256) void pack_kernel(const float* __restrict__ feat,
                                                   __half* __restrict__ fh) {
    const int wave = threadIdx.x >> 6;
    const int lane = threadIdx.x & 63;
    const int row  = blockIdx.x * 4 + wave;              // 0..8191
    const float4 v = ((const float4*)(feat + (size_t)row * DD))[lane];
    float s = fmaf(v.x, v.x, fmaf(v.y, v.y, fmaf(v.z, v.z, v.w * v.w)));
#pragma unroll
    for (int off = 32; off >= 1; off >>= 1) s += __shfl_xor(s, off, 64);
    float rn = rsqrtf(s);
    rn = rn * (1.5f - 0.5f * s * rn * rn);               // one Newton step (f32-exact norm)
    __half2* dst = (__half2*)(fh + (size_t)row * DD);
    dst[2 * lane + 0] = __floats2half2_rn(v.x * rn, v.y * rn);
    dst[2 * lane + 1] = __floats2half2_rn(v.z * rn, v.w * rn);
}

// Kernel 2: block = (pair, n-tile of 32, m-half of 1024).
// Scan: points direct from global (L2), prefetched 1 chunk ahead. Sparse
// hits -> per-wave LDS queue. Tail: 16 hits in parallel (4 lanes/hit),
// cos = dot of unit-fp16 rows (8 float4 loads per row-lane, no norms).
// No global atomics: partials to private slots.
__global__ __launch_bounds__(256) void scan_kernel(const __half* __restrict__ fh,
                                                   const float* __restrict__ pts_src,
                                                   const float* __restrict__ pts_dst,
                                                   const int* __restrict__ hptr,
                                                   const int* __restrict__ wptr,
                                                   float* __restrict__ psum,
                                                   unsigned int* __restrict__ pcnt) {
    __shared__ unsigned int wq[4][WQ_CAP];               // per-wave hit queues
    __shared__ unsigned int wqc[4];
    __shared__ float bsum[4];
    __shared__ unsigned int bcnt[4];
    const int pair  = blockIdx.x >> 7;                   // / (NT*MSPLIT)
    const int tile  = (blockIdx.x >> 1) & (NT - 1);
    const int mhalf = blockIdx.x & 1;
    const int mbase = mhalf * MLEN;
    const int i = pair >> 2;
    const int j = pair & 3;
    const float sx = ((float)(*wptr) - 1.0f) * 0.5f;
    const float sy = ((float)(*hptr) - 1.0f) * 0.5f;

    const int wave = threadIdx.x >> 6;
    const int lane = threadIdx.x & 63;
    if (lane == 0) wqc[wave] = 0u;                       // same-wave order: no barrier

    const int nbase = tile * TILE_N + wave * NPW;
    float psx[NPW], psy[NPW];
#pragma unroll
    for (int k = 0; k < NPW; ++k) {
        psx[k] = fmaf(pts_src[(size_t)(i * NN + nbase + k) * 2 + 0], sx, sx);
        psy[k] = fmaf(pts_src[(size_t)(i * NN + nbase + k) * 2 + 1], sy, sy);
    }

    // lane's view of this block's m-half: float4 = 2 raw points
    const float4* pd = (const float4*)(pts_dst + (size_t)pair * NN * 2 + (size_t)mbase * 2);

    float4 q = pd[lane];                                 // prefetch chunk 0
#pragma unroll
    for (int c = 0; c < MCH; ++c) {
        float4 qn;
        if (c + 1 < MCH) qn = pd[(c + 1) * 64 + lane];   // prefetch next
        const float qx0 = fmaf(q.x, sx, sx), qy0 = fmaf(q.y, sy, sy);
        const float qx1 = fmaf(q.z, sx, sx), qy1 = fmaf(q.w, sy, sy);
        float mn = 1e30f;
#pragma unroll
        for (int k = 0; k < NPW; ++k) {
            const float ax = psx[k] - qx0, ay = psy[k] - qy0;
            const float bx = psx[k] - qx1, by = psy[k] - qy1;
            mn = fminf(mn, fminf(fmaf(ax, ax, ay * ay), fmaf(bx, bx, by * by)));
        }
        if (__ballot(mn <= 64.0f)) {                     // ~49% of chunks: recompute
            const unsigned int m2 = (unsigned int)(mbase + c * 128 + 2 * lane);
#pragma unroll
            for (int k = 0; k < NPW; ++k) {
                const float ax = psx[k] - qx0, ay = psy[k] - qy0;
                const float bx = psx[k] - qx1, by = psy[k] - qy1;
                const float d0 = fmaf(ax, ax, ay * ay);
                const float d1 = fmaf(bx, bx, by * by);
                if (fminf(d0, d1) <= 64.0f) {            // per-k early-out
                    if (d0 <= 64.0f) {
                        const unsigned int slot = atomicAdd(&wqc[wave], 1u);
                        if (slot < WQ_CAP) wq[wave][slot] = ((unsigned int)k << 11) | m2;
                    }
                    if (d1 <= 64.0f) {
                        const unsigned int slot = atomicAdd(&wqc[wave], 1u);
                        if (slot < WQ_CAP) wq[wave][slot] = ((unsigned int)k << 11) | (m2 + 1u);
                    }
                }
            }
        }
        q = qn;
    }

    // ---- tail: 16 hits at a time, 4 lanes/hit; cos = unit-fp16 dot ----
    const unsigned int hc = min(wqc[wave], (unsigned int)WQ_CAP);
    const int g = lane >> 2, sub = lane & 3;
    float lsum = 0.0f;
    for (unsigned int h0 = 0; h0 < hc; h0 += 16) {
        const unsigned int hid = h0 + (unsigned int)g;
        const bool valid = hid < hc;
        float dd = 0.0f;
        if (valid) {
            const unsigned int rec = wq[wave][hid];
            const int m = (int)(rec & 2047u);
            const int n = nbase + (int)(rec >> 11);
            // one unit row = 256 halves = 512 B = 32 float4; 8 per sub-lane
            const float4* pa = (const float4*)(fh + (size_t)(j * NN + n) * DD);
            const float4* pb = (const float4*)(fh + (size_t)(i * NN + m) * DD);
#pragma unroll
            for (int t = 0; t < 8; ++t) {
                const float4 A = pa[t * 4 + sub];
                const float4 B = pb[t * 4 + sub];
                const __half2* ah = (const __half2*)&A;
                const __half2* bh = (const __half2*)&B;
#pragma unroll
                for (int u = 0; u < 4; ++u) {
                    const float2 fa2 = __half22float2(ah[u]);
                    const float2 fb2 = __half22float2(bh[u]);
                    dd = fmaf(fa2.x, fb2.x, fmaf(fa2.y, fb2.y, dd));
                }
            }
        }
        dd += __shfl_xor(dd, 1, 64);
        dd += __shfl_xor(dd, 2, 64);
        if (valid && sub == 0) lsum += 1.0f - dd;
    }
#pragma unroll
    for (int off = 32; off >= 1; off >>= 1) lsum += __shfl_xor(lsum, off, 64);

    // ---- block reduction -> private slot (plain stores, no atomics) ----
    if (lane == 0) { bsum[wave] = lsum; bcnt[wave] = hc; }
    __syncthreads();
    if (threadIdx.x == 0) {
        psum[blockIdx.x] = bsum[0] + bsum[1] + bsum[2] + bsum[3];
        pcnt[blockIdx.x] = bcnt[0] + bcnt[1] + bcnt[2] + bcnt[3];
    }
}

// Kernel 3: reduce the 2048 block partials. One block.
__global__ __launch_bounds__(256) void finalize_kernel(const float* __restrict__ psum,
                                                       const unsigned int* __restrict__ pcnt,
                                                       float* __restrict__ out) {
    float s = 0.0f;
    float c = 0.0f;                                      // hits < 2^24, exact in f32
    for (int t = threadIdx.x; t < NBLK; t += 256) {
        s += psum[t];
        c += (float)pcnt[t];
    }
#pragma unroll
    for (int off = 32; off >= 1; off >>= 1) {
        s += __shfl_xor(s, off, 64);
        c += __shfl_xor(c, off, 64);
    }
    __shared__ float ss[4], cc[4];
    const int wave = threadIdx.x >> 6;
    const int lane = threadIdx.x & 63;
    if (lane == 0) { ss[wave] = s; cc[wave] = c; }
    __syncthreads();
    if (threadIdx.x == 0) {
        const float S = ss[0] + ss[1] + ss[2] + ss[3];
        const float C = cc[0] + cc[1] + cc[2] + cc[3];
        out[0] = S / fmaxf(C, 1.0f);                     // max(cnt, 1)
    }
}

extern "C" void kernel_launch(void* const* d_in, const int* in_sizes, int n_in,
                              void* d_out, int out_size, void* d_ws, size_t ws_size,
                              hipStream_t stream) {
    const float* feat    = (const float*)d_in[0];   // [B,N,D] f32
    const float* pts_src = (const float*)d_in[1];   // [B,N,2] f32
    const float* pts_dst = (const float*)d_in[2];   // [B,B,N,2] f32
    // d_in[3] = invis_idx — unused by the reference
    const int* hptr = (const int*)d_in[4];          // height (scalar)
    const int* wptr = (const int*)d_in[5];          // width  (scalar)
    float* out = (float*)d_out;

    float*        psum = (float*)d_ws;                           // 8 KB
    unsigned int* pcnt = (unsigned int*)((char*)d_ws + 8192);    // 8 KB
    __half*       fh   = (__half*)((char*)d_ws + 65536);         // 4 MB unit-fp16 rows

    pack_kernel<<<BB * NN / 4, 256, 0, stream>>>(feat, fh);
    scan_kernel<<<NBLK, 256, 0, stream>>>(fh, pts_src, pts_dst,
                                          hptr, wptr, psum, pcnt);
    finalize_kernel<<<1, 256, 0, stream>>>(psum, pcnt, out);
}